// Round 3
// baseline (1754.907 us; speedup 1.0000x reference)
//
#include <hip/hip_runtime.h>
#include <hip/hip_bf16.h>
#include <math.h>

#define NNODES 8000
#define NP1    8001
#define H      256
#define CAP    64
#define TSTEPS 8
#define MTOT   (2*NP1)    // 16002
#define MPAD   16128      // 126 * 128
#define NROWBLK 251       // ceil(8001/32)

typedef __attribute__((ext_vector_type(8))) short short8;
typedef __attribute__((ext_vector_type(4))) float floatx4;

// ---------------- build ELL: one row per block, LDS compaction ---------------------
__global__ __launch_bounds__(256) void build_ell_kernel(
    const float* __restrict__ adj_b, const float* __restrict__ adj_a,
    int* __restrict__ counts, int* __restrict__ colidx)
{
  int b = blockIdx.x;             // 0..15999
  int g = b >= NNODES;
  int row = b - g * NNODES;
  const float* adj = (g ? adj_a : adj_b) + (size_t)row * NNODES;
  __shared__ int cnt;
  if (threadIdx.x == 0) cnt = 0;
  __syncthreads();
  int* dst = colidx + (size_t)b * CAP;
  for (int base = threadIdx.x * 4; base < NNODES; base += 1024) {
    float4 v = *(const float4*)(adj + base);
    #pragma unroll
    for (int u = 0; u < 4; ++u) {
      if ((&v.x)[u] != 0.0f) {
        int s = atomicAdd(&cnt, 1);
        if (s < CAP) dst[s] = base + u;
      }
    }
  }
  __syncthreads();
  if (threadIdx.x == 0) counts[b] = cnt < CAP ? cnt : CAP;
}

// ---- Wbig [1024,512] bf16: gate-interleaved [Wc | Whh]; bc = W_ih @ b_lin ---------
// Row p: ct=p>>7, wn2=(p&127)>>6, jj=((p&127)>>4)&3, lm=p&15; unit c=ct*32+wn2*16+lm.
// cols 0..255  (applied to hagg): jj=0->Wc[c], jj=1->Wc[256+c], jj=2->Wc[512+c], jj=3->0
// cols 256..511 (applied to h):   jj=0->Whh[c], jj=1->Whh[256+c], jj=2->0, jj=3->Whh[512+c]
__global__ __launch_bounds__(256) void weights_kernel(
    const float* __restrict__ Wih, const float* __restrict__ Wlin,
    const float* __restrict__ blin, const float* __restrict__ Whh,
    __hip_bfloat16* __restrict__ Wbig, float* __restrict__ bc)
{
  __shared__ float srow[H];
  __shared__ float red[256];
  int p = blockIdx.x;             // 0..1023
  int ct = p >> 7, within = p & 127;
  int wn2 = within >> 6, jj = (within >> 4) & 3, lm = within & 15;
  int c = ct * 32 + wn2 * 16 + lm;
  int t = threadIdx.x;
  size_t ob = (size_t)p * 512;
  if (jj < 3) {
    int gr = jj * 256 + c;
    srow[t] = Wih[(size_t)gr * H + t];
    __syncthreads();
    float acc = 0.f;
    #pragma unroll 8
    for (int k = 0; k < H; ++k) acc += srow[k] * Wlin[(size_t)k * H + t];
    Wbig[ob + t] = __float2bfloat16(acc);
    red[t] = srow[t] * blin[t];
    __syncthreads();
    for (int s = 128; s > 0; s >>= 1) { if (t < s) red[t] += red[t + s]; __syncthreads(); }
    if (t == 0) bc[gr] = red[0];
  } else {
    Wbig[ob + t] = __float2bfloat16(0.f);
  }
  int grh = (jj == 0) ? c : (jj == 1) ? 256 + c : 512 + c;  // unused when jj==2
  Wbig[ob + 256 + t] = (jj == 2) ? __float2bfloat16(0.f)
                                 : __float2bfloat16(Whh[(size_t)grh * H + t]);
}

// ---------------- init h (fp32 + bf16 ping buffer), colsum -> cs0 ------------------
__global__ __launch_bounds__(256) void init_h_kernel(
    const float* __restrict__ bx, const float* __restrict__ ax,
    float* __restrict__ h, __hip_bfloat16* __restrict__ hbf, float* __restrict__ cs0)
{
  int b = blockIdx.x;
  int g = b / NROWBLK, rb = b - g * NROWBLK;
  int t = threadIdx.x;
  const float* x = g ? ax : bx;
  float local = 0.f;
  for (int q = 0; q < 32; ++q) {
    int r = rb * 32 + q;
    if (r >= NP1) break;
    size_t off = ((size_t)g * NP1 + r) * H + t;
    float v = 0.f;
    if (r < NNODES) { v = x[(size_t)r * H + t]; local += v; }
    h[off] = v;
    hbf[off] = __float2bfloat16(v);
  }
  atomicAdd(&cs0[g * H + t], local);
}

// ---------------- hagg_bf = bf16(A @ h)  (ELL gather; supernode = colsum) ----------
__global__ __launch_bounds__(256) void spmm_kernel(
    const __hip_bfloat16* __restrict__ hbf, __hip_bfloat16* __restrict__ haggbf,
    const int* __restrict__ counts, const int* __restrict__ colidx,
    const float* __restrict__ cs)
{
  int b = blockIdx.x;             // 0..16001
  int g = b / NP1, r = b - g * NP1;
  int t = threadIdx.x;
  size_t outoff = ((size_t)g * NP1 + r) * H + t;
  if (r == NNODES) { haggbf[outoff] = __float2bfloat16(cs[g * H + t]); return; }
  int rbase = g * NNODES + r;
  int cnt = counts[rbase];
  const int* cols = colidx + (size_t)rbase * CAP;
  const __hip_bfloat16* hg = hbf + (size_t)g * NP1 * H;
  float acc = 0.f;
  int k = 0;
  for (; k + 4 <= cnt; k += 4) {
    int c0 = cols[k], c1 = cols[k + 1], c2 = cols[k + 2], c3 = cols[k + 3];
    float v0 = __bfloat162float(hg[(size_t)c0 * H + t]);
    float v1 = __bfloat162float(hg[(size_t)c1 * H + t]);
    float v2 = __bfloat162float(hg[(size_t)c2 * H + t]);
    float v3 = __bfloat162float(hg[(size_t)c3 * H + t]);
    acc += v0 + v1 + v2 + v3;
  }
  for (; k < cnt; ++k)
    acc += __bfloat162float(hg[(size_t)cols[k] * H + t]);
  haggbf[outoff] = __float2bfloat16(acc);
}

// ------- fused [hagg|h] @ Wbig^T (bf16 MFMA, K=512) + GRU epilogue -----------------
// Block: 128 rows x 32 hidden units (128 cols of Wbig, gate-interleaved at 16).
// Per wave: jj=0 -> ir+hr sum, jj=1 -> iz+hz, jj=2 -> in (i-half only),
// jj=3 -> hn (h-half only). All 4 gates for (row,unit) live in one lane's accs.
__global__ __launch_bounds__(256) void fused_gemm_gru_kernel(
    const __hip_bfloat16* __restrict__ haggbf, const __hip_bfloat16* __restrict__ hin,
    const __hip_bfloat16* __restrict__ Wbig, const int* __restrict__ counts,
    const float* __restrict__ bc, const float* __restrict__ bih,
    const float* __restrict__ bhh,
    float* __restrict__ h, __hip_bfloat16* __restrict__ hout,
    float* __restrict__ cs_next)
{
  __shared__ __align__(16) short lsA[128 * 32];
  __shared__ __align__(16) short lsB[128 * 32];
  int ct = blockIdx.y;                     // 0..7
  int m0 = blockIdx.x * 128;
  const short* Bb = (const short*)Wbig + (size_t)ct * 128 * 512;
  int t = threadIdx.x;
  int w = t >> 6, l = t & 63;
  int lr = l >> 2, lc = l & 3;
  int wm = (w & 1) * 64, wn = (w >> 1) * 64;
  int q = l >> 4, lm = l & 15;
  floatx4 acc[4][4] = {};

  for (int k0 = 0; k0 < 512; k0 += 32) {
    bool ihalf = (k0 < 256);
    const short* Asrc = ihalf ? (const short*)haggbf : (const short*)hin;
    int ka = ihalf ? k0 : k0 - 256;
    #pragma unroll
    for (int j = 0; j < 2; ++j) {
      int r = j * 64 + w * 16 + lr;
      int cch = lc ^ ((r >> 1) & 3);
      const short* ga = Asrc + (size_t)(m0 + r) * H + ka + cch * 8;
      const short* gb = Bb + (size_t)r * 512 + k0 + cch * 8;
      short* la = lsA + (j * 64 + w * 16) * 32;
      short* lb = lsB + (j * 64 + w * 16) * 32;
      __builtin_amdgcn_global_load_lds((const __attribute__((address_space(1))) void*)ga,
                                       (__attribute__((address_space(3))) void*)la, 16, 0, 0);
      __builtin_amdgcn_global_load_lds((const __attribute__((address_space(1))) void*)gb,
                                       (__attribute__((address_space(3))) void*)lb, 16, 0, 0);
    }
    __syncthreads();
    short8 af[4], bfr[4];
    #pragma unroll
    for (int i = 0; i < 4; ++i) {
      int m = wm + i * 16 + lm;
      af[i] = *(const short8*)&lsA[m * 32 + (q ^ ((m >> 1) & 3)) * 8];
      int n = wn + i * 16 + lm;
      bfr[i] = *(const short8*)&lsB[n * 32 + (q ^ ((n >> 1) & 3)) * 8];
    }
    #pragma unroll
    for (int i = 0; i < 4; ++i) {
      acc[i][0] = __builtin_amdgcn_mfma_f32_16x16x32_bf16(af[i], bfr[0], acc[i][0], 0, 0, 0);
      acc[i][1] = __builtin_amdgcn_mfma_f32_16x16x32_bf16(af[i], bfr[1], acc[i][1], 0, 0, 0);
      if (ihalf)
        acc[i][2] = __builtin_amdgcn_mfma_f32_16x16x32_bf16(af[i], bfr[2], acc[i][2], 0, 0, 0);
      else
        acc[i][3] = __builtin_amdgcn_mfma_f32_16x16x32_bf16(af[i], bfr[3], acc[i][3], 0, 0, 0);
    }
    __syncthreads();
  }

  // ---- GRU epilogue: lane owns unit c, rows wm+i*16+q*4+reg ----
  int c = ct * 32 + (w >> 1) * 16 + lm;
  float bcr = bc[c], bcz = bc[256 + c], bcn = bc[512 + c];
  float br  = bih[c] + bhh[c];
  float bz  = bih[256 + c] + bhh[256 + c];
  float bin = bih[512 + c];
  float bhn = bhh[512 + c];
  float local0 = 0.f, local1 = 0.f;
  #pragma unroll
  for (int i = 0; i < 4; ++i) {
    #pragma unroll
    for (int reg = 0; reg < 4; ++reg) {
      int row = m0 + wm + i * 16 + q * 4 + reg;
      if (row >= MTOT) continue;
      int g = row >= NP1;
      int r = row - g * NP1;
      float deg = (r < NNODES) ? (float)counts[g * NNODES + r] : (float)NNODES;
      float rz  = acc[i][0][reg] + deg * bcr + br;
      float zz  = acc[i][1][reg] + deg * bcz + bz;
      float in_ = acc[i][2][reg] + deg * bcn + bin;
      float hn  = acc[i][3][reg] + bhn;
      float rg = 1.f / (1.f + expf(-rz));
      float z  = 1.f / (1.f + expf(-zz));
      float n  = tanhf(in_ + rg * hn);
      size_t hoff = (size_t)row * H + c;
      float hp = h[hoff];
      float hnew = (1.f - z) * n + z * hp;
      h[hoff] = hnew;
      hout[hoff] = __float2bfloat16(hnew);
      if (r < NNODES) { if (g) local1 += hnew; else local0 += hnew; }
    }
  }
  if (local0 != 0.f) atomicAdd(&cs_next[c], local0);
  if (local1 != 0.f) atomicAdd(&cs_next[256 + c], local1);
}

// ---------------- final logits + log_softmax ---------------------------------------
__global__ __launch_bounds__(256) void final_kernel(
    const float* __restrict__ h, const float* __restrict__ Wfc,
    const float* __restrict__ bfc, float* __restrict__ out)
{
  __shared__ float red0[256];
  __shared__ float red1[256];
  int t = threadIdx.x;
  float sn0 = h[(size_t)NNODES * H + t];              // b supernode
  float sn1 = h[((size_t)NP1 + NNODES) * H + t];      // a supernode
  red0[t] = sn0 * Wfc[t]       + sn1 * Wfc[H + t];
  red1[t] = sn0 * Wfc[512 + t] + sn1 * Wfc[512 + H + t];
  __syncthreads();
  for (int s = 128; s > 0; s >>= 1) {
    if (t < s) { red0[t] += red0[t + s]; red1[t] += red1[t + s]; }
    __syncthreads();
  }
  if (t == 0) {
    float l0 = red0[0] + bfc[0], l1 = red1[0] + bfc[1];
    float m = fmaxf(l0, l1);
    float lse = m + logf(expf(l0 - m) + expf(l1 - m));
    out[0] = l0 - lse;
    out[1] = l1 - lse;
  }
}

extern "C" void kernel_launch(void* const* d_in, const int* in_sizes, int n_in,
                              void* d_out, int out_size, void* d_ws, size_t ws_size,
                              hipStream_t stream) {
  const float* b_x   = (const float*)d_in[0];
  const float* b_adj = (const float*)d_in[1];
  const float* a_x   = (const float*)d_in[2];
  const float* a_adj = (const float*)d_in[3];
  const float* Wlin  = (const float*)d_in[4];
  const float* blin  = (const float*)d_in[5];
  const float* Wih   = (const float*)d_in[6];
  const float* bih   = (const float*)d_in[7];
  const float* Whh   = (const float*)d_in[8];
  const float* bhh   = (const float*)d_in[9];
  const float* Wfc   = (const float*)d_in[10];
  const float* bfc   = (const float*)d_in[11];
  float* out = (float*)d_out;

  char* ws = (char*)d_ws;
  size_t off = 0;
  auto alloc = [&](size_t bytes) {
    void* p = ws + off;
    off += (bytes + 255) & ~(size_t)255;
    return p;
  };
  float* h               = (float*)alloc((size_t)MTOT * H * 4);            // 16.4 MB
  __hip_bfloat16* hbf0   = (__hip_bfloat16*)alloc((size_t)MPAD * H * 2);   // 8.3 MB
  __hip_bfloat16* hbf1   = (__hip_bfloat16*)alloc((size_t)MPAD * H * 2);   // 8.3 MB
  __hip_bfloat16* haggbf = (__hip_bfloat16*)alloc((size_t)MPAD * H * 2);   // 8.3 MB
  __hip_bfloat16* Wbig   = (__hip_bfloat16*)alloc((size_t)1024 * 512 * 2); // 1.0 MB
  float* bc              = (float*)alloc((size_t)768 * 4);
  int* colidx            = (int*)alloc((size_t)2 * NNODES * CAP * 4);      // 4.1 MB
  int* counts            = (int*)alloc((size_t)2 * NNODES * 4);
  float* cs              = (float*)alloc((size_t)(TSTEPS + 1) * 2 * H * 4);

  hipMemsetAsync(cs, 0, (size_t)(TSTEPS + 1) * 2 * H * 4, stream);

  build_ell_kernel<<<2 * NNODES, 256, 0, stream>>>(b_adj, a_adj, counts, colidx);
  weights_kernel<<<1024, 256, 0, stream>>>(Wih, Wlin, blin, Whh, Wbig, bc);
  init_h_kernel<<<2 * NROWBLK, 256, 0, stream>>>(b_x, a_x, h, hbf0, cs);

  __hip_bfloat16* ping[2] = { hbf0, hbf1 };
  for (int t = 0; t < TSTEPS; ++t) {
    __hip_bfloat16* hin  = ping[t & 1];
    __hip_bfloat16* hout = ping[(t + 1) & 1];
    spmm_kernel<<<MTOT, 256, 0, stream>>>(hin, haggbf, counts, colidx, cs + t * 2 * H);
    fused_gemm_gru_kernel<<<dim3(MPAD / 128, 8), 256, 0, stream>>>(
        haggbf, hin, Wbig, counts, bc, bih, bhh, h, hout, cs + (t + 1) * 2 * H);
  }
  final_kernel<<<1, 256, 0, stream>>>(h, Wfc, bfc, out);
}

// Round 4
// 1165.910 us; speedup vs baseline: 1.5052x; 1.5052x over previous
//
#include <hip/hip_runtime.h>
#include <hip/hip_bf16.h>
#include <math.h>

#define NNODES 8000
#define NP1    8001
#define H      256
#define CAP    64
#define TSTEPS 8
#define MTOT   (2*NP1)    // 16002
#define MPAD   16128      // 63 * 256
#define NRB    (MPAD/32)  // 504

typedef __attribute__((ext_vector_type(8))) short short8;
typedef __attribute__((ext_vector_type(4))) float floatx4;

__device__ __forceinline__ float bl2f(unsigned short u) {
  union { unsigned int i; float f; } z; z.i = ((unsigned int)u) << 16; return z.f;
}
__device__ __forceinline__ unsigned short f2bl(float f) {
  __hip_bfloat16 b = __float2bfloat16(f);
  return *(unsigned short*)&b;
}
__device__ __forceinline__ float sigf(float x) { return 1.f / (1.f + __expf(-x)); }
__device__ __forceinline__ float tanhf_fast(float x) { return 2.f / (1.f + __expf(-2.f * x)) - 1.f; }

// ---------------- build ELL: one row per WAVE, 4 rows/block ------------------------
__global__ __launch_bounds__(256) void build_ell_kernel(
    const float* __restrict__ adj_b, const float* __restrict__ adj_a,
    int* __restrict__ counts, int* __restrict__ colidx)
{
  __shared__ int cnt[4];
  int w = threadIdx.x >> 6, l = threadIdx.x & 63;
  int b = blockIdx.x * 4 + w;     // grid 4000 -> b < 16000
  int g = b >= NNODES;
  int row = b - g * NNODES;
  const float* adj = (g ? adj_a : adj_b) + (size_t)row * NNODES;
  if (l == 0) cnt[w] = 0;
  int* dst = colidx + (size_t)b * CAP;
  for (int base = l * 4; base < NNODES; base += 1024) {
    int b1 = base + 256, b2 = base + 512, b3 = base + 768;
    bool p1 = b1 < NNODES, p2 = b2 < NNODES, p3 = b3 < NNODES;
    float4 v0 = *(const float4*)(adj + base);
    float4 v1 = p1 ? *(const float4*)(adj + b1) : make_float4(0,0,0,0);
    float4 v2 = p2 ? *(const float4*)(adj + b2) : make_float4(0,0,0,0);
    float4 v3 = p3 ? *(const float4*)(adj + b3) : make_float4(0,0,0,0);
    #pragma unroll
    for (int u = 0; u < 4; ++u) {
      if ((&v0.x)[u] != 0.f) { int s = atomicAdd(&cnt[w], 1); if (s < CAP) dst[s] = base + u; }
    }
    #pragma unroll
    for (int u = 0; u < 4; ++u) {
      if ((&v1.x)[u] != 0.f) { int s = atomicAdd(&cnt[w], 1); if (s < CAP) dst[s] = b1 + u; }
    }
    #pragma unroll
    for (int u = 0; u < 4; ++u) {
      if ((&v2.x)[u] != 0.f) { int s = atomicAdd(&cnt[w], 1); if (s < CAP) dst[s] = b2 + u; }
    }
    #pragma unroll
    for (int u = 0; u < 4; ++u) {
      if ((&v3.x)[u] != 0.f) { int s = atomicAdd(&cnt[w], 1); if (s < CAP) dst[s] = b3 + u; }
    }
  }
  if (l == 0) counts[b] = cnt[w] < CAP ? cnt[w] : CAP;
}

// ---------------- degf[row] for row-space [MPAD] -----------------------------------
__global__ __launch_bounds__(256) void degf_kernel(
    const int* __restrict__ counts, float* __restrict__ degf)
{
  int row = blockIdx.x * 256 + threadIdx.x;   // grid 63
  float d = 0.f;
  if (row < MTOT) {
    int g = row >= NP1;
    int r = row - g * NP1;
    if (r < NNODES) d = (float)counts[g * NNODES + r];
    else if (r == NNODES) d = (float)NNODES;
  }
  degf[row] = d;
}

// ---- Wbig2 [768,512] bf16, n-packed gate-interleave; bc = W_ih @ b_lin ------------
// Row p: ct=p/96, w96=p%96, gb=w96>>4 (0..5), u=p&15; jj=gb>>1 (gate r,z,n), uh=gb&1.
// unit c = ct*32 + uh*16 + u; gr = jj*256 + c.
// Row content: [0:256]=(Wih@Wlin)[gr], [256:512]=Whh[gr].  (no zero rows)
__global__ __launch_bounds__(256) void weights_kernel(
    const float* __restrict__ Wih, const float* __restrict__ Wlin,
    const float* __restrict__ blin, const float* __restrict__ Whh,
    __hip_bfloat16* __restrict__ Wbig2, float* __restrict__ bc)
{
  __shared__ float srow[H];
  __shared__ float red[256];
  int p = blockIdx.x;             // 0..767
  int ct = p / 96, w96 = p - ct * 96;
  int gb = w96 >> 4, u = w96 & 15;
  int jj = gb >> 1, uh = gb & 1;
  int c = ct * 32 + uh * 16 + u;
  int gr = jj * 256 + c;
  int t = threadIdx.x;
  size_t ob = (size_t)p * 512;
  srow[t] = Wih[(size_t)gr * H + t];
  __syncthreads();
  float acc = 0.f;
  #pragma unroll 8
  for (int k = 0; k < H; ++k) acc += srow[k] * Wlin[(size_t)k * H + t];
  Wbig2[ob + t] = __float2bfloat16(acc);
  Wbig2[ob + 256 + t] = __float2bfloat16(Whh[(size_t)gr * H + t]);
  red[t] = srow[t] * blin[t];
  __syncthreads();
  for (int s = 128; s > 0; s >>= 1) { if (t < s) red[t] += red[t + s]; __syncthreads(); }
  if (t == 0) bc[gr] = red[0];
}

// ---------------- init h (fp32 + bf16) over MPAD rows, colsum -> cs0 ---------------
__global__ __launch_bounds__(256) void init_h_kernel(
    const float* __restrict__ bx, const float* __restrict__ ax,
    float* __restrict__ h, __hip_bfloat16* __restrict__ hbf, float* __restrict__ cs0)
{
  int b = blockIdx.x;             // 0..503
  int t = threadIdx.x;
  float l0 = 0.f, l1 = 0.f;
  for (int q = 0; q < 32; ++q) {
    int row = b * 32 + q;
    int g = row >= NP1;
    int r = row - g * NP1;
    float v = 0.f;
    if (r < NNODES) {
      v = (g ? ax : bx)[(size_t)r * H + t];
      if (g) l1 += v; else l0 += v;
    }
    size_t off = (size_t)row * H + t;
    h[off] = v;
    hbf[off] = __float2bfloat16(v);
  }
  if (l0 != 0.f) atomicAdd(&cs0[t], l0);
  if (l1 != 0.f) atomicAdd(&cs0[256 + t], l1);
}

// ---------------- hagg_bf = bf16(A @ h): wave-per-row gather -----------------------
__global__ __launch_bounds__(256) void spmm_kernel(
    const unsigned short* __restrict__ hbf, unsigned short* __restrict__ haggbf,
    const int* __restrict__ counts, const int* __restrict__ colidx,
    const float* __restrict__ cs)
{
  int w = threadIdx.x >> 6, l = threadIdx.x & 63;
  int b = blockIdx.x * 4 + w;     // grid 4001
  if (b >= MTOT) return;
  int g = b >= NP1;
  int r = b - g * NP1;
  size_t outoff = (size_t)b * H + l * 4;
  if (r == NNODES) {
    float4 v = *(const float4*)&cs[g * H + l * 4];
    ushort4 o; o.x = f2bl(v.x); o.y = f2bl(v.y); o.z = f2bl(v.z); o.w = f2bl(v.w);
    *(ushort4*)(haggbf + outoff) = o;
    return;
  }
  int rb = g * NNODES + r;
  int cnt = counts[rb];
  const int* cols = colidx + (size_t)rb * CAP;
  const unsigned short* hg = hbf + (size_t)g * NP1 * H;
  float a0 = 0.f, a1 = 0.f, a2 = 0.f, a3 = 0.f;
  int k = 0;
  for (; k + 4 <= cnt; k += 4) {
    int c0 = cols[k], c1 = cols[k+1], c2 = cols[k+2], c3 = cols[k+3];
    uint2 x0 = *(const uint2*)(hg + (size_t)c0 * H + l * 4);
    uint2 x1 = *(const uint2*)(hg + (size_t)c1 * H + l * 4);
    uint2 x2 = *(const uint2*)(hg + (size_t)c2 * H + l * 4);
    uint2 x3 = *(const uint2*)(hg + (size_t)c3 * H + l * 4);
    a0 += bl2f(x0.x & 0xffff) + bl2f(x1.x & 0xffff) + bl2f(x2.x & 0xffff) + bl2f(x3.x & 0xffff);
    a1 += bl2f(x0.x >> 16)    + bl2f(x1.x >> 16)    + bl2f(x2.x >> 16)    + bl2f(x3.x >> 16);
    a2 += bl2f(x0.y & 0xffff) + bl2f(x1.y & 0xffff) + bl2f(x2.y & 0xffff) + bl2f(x3.y & 0xffff);
    a3 += bl2f(x0.y >> 16)    + bl2f(x1.y >> 16)    + bl2f(x2.y >> 16)    + bl2f(x3.y >> 16);
  }
  for (; k < cnt; ++k) {
    uint2 x = *(const uint2*)(hg + (size_t)cols[k] * H + l * 4);
    a0 += bl2f(x.x & 0xffff); a1 += bl2f(x.x >> 16);
    a2 += bl2f(x.y & 0xffff); a3 += bl2f(x.y >> 16);
  }
  ushort4 o; o.x = f2bl(a0); o.y = f2bl(a1); o.z = f2bl(a2); o.w = f2bl(a3);
  *(ushort4*)(haggbf + outoff) = o;
}

// ------- fused [hagg|h] @ Wbig2^T (bf16 MFMA, K=512) + GRU epilogue ----------------
// Block: 256 rows x 32 units (B-tile 96 rows, n-packed). 4 waves: 2 row-halves x
// 2 unit-halves; per wave 8x3 frag tile -> 24 MFMAs / 11 ds_read_b128 per k-step.
// acc slots: 0=r(ir+hr), 1=z(iz+hz), 2=in (i-phase, Wc_n), 3=hn (h-phase, Whh_n).
__global__ __launch_bounds__(256, 2) void fused_gemm_gru_kernel(
    const __hip_bfloat16* __restrict__ haggbf, const __hip_bfloat16* __restrict__ hin,
    const __hip_bfloat16* __restrict__ Wbig2, const float* __restrict__ degf,
    const float* __restrict__ bc, const float* __restrict__ bih,
    const float* __restrict__ bhh,
    float* __restrict__ h, __hip_bfloat16* __restrict__ hout,
    float* __restrict__ cs_next)
{
  __shared__ __align__(16) short lsA[256 * 32];
  __shared__ __align__(16) short lsB[96 * 32];
  int ct = blockIdx.y;                     // 0..7
  int m0 = blockIdx.x * 256;               // grid.x = 63
  const short* Bbase = (const short*)Wbig2 + (size_t)ct * 96 * 512;
  int t = threadIdx.x;
  int w = t >> 6, l = t & 63;
  int lr = l >> 2, lc = l & 3;
  int wm = (w & 1) * 128, uh = w >> 1;
  int q = l >> 4, lm = l & 15;
  floatx4 acc[8][4] = {};

  for (int k0 = 0; k0 < 512; k0 += 32) {
    bool ihalf = (k0 < 256);
    const short* Asrc = ihalf ? (const short*)haggbf : (const short*)hin;
    int ka = k0 & 255;
    #pragma unroll
    for (int j = 0; j < 4; ++j) {
      int r = w * 64 + j * 16 + lr;
      int cch = lc ^ ((r >> 1) & 3);
      const short* ga = Asrc + (size_t)(m0 + r) * H + ka + cch * 8;
      short* la = lsA + (w * 64 + j * 16) * 32;
      __builtin_amdgcn_global_load_lds((const __attribute__((address_space(1))) void*)ga,
                                       (__attribute__((address_space(3))) void*)la, 16, 0, 0);
    }
    if (w < 3) {
      #pragma unroll
      for (int j = 0; j < 2; ++j) {
        int r = (w * 2 + j) * 16 + lr;           // 0..95
        int cch = lc ^ ((r >> 1) & 3);
        const short* gb = Bbase + (size_t)r * 512 + k0 + cch * 8;
        short* lb = lsB + (w * 2 + j) * 16 * 32;
        __builtin_amdgcn_global_load_lds((const __attribute__((address_space(1))) void*)gb,
                                         (__attribute__((address_space(3))) void*)lb, 16, 0, 0);
      }
    }
    __syncthreads();
    short8 bfr[3];
    #pragma unroll
    for (int jj = 0; jj < 3; ++jj) {
      int n = (jj * 2 + uh) * 16 + lm;
      bfr[jj] = *(const short8*)&lsB[n * 32 + (q ^ ((n >> 1) & 3)) * 8];
    }
    #pragma unroll
    for (int i = 0; i < 8; ++i) {
      int m = wm + i * 16 + lm;
      short8 af = *(const short8*)&lsA[m * 32 + (q ^ ((m >> 1) & 3)) * 8];
      acc[i][0] = __builtin_amdgcn_mfma_f32_16x16x32_bf16(af, bfr[0], acc[i][0], 0, 0, 0);
      acc[i][1] = __builtin_amdgcn_mfma_f32_16x16x32_bf16(af, bfr[1], acc[i][1], 0, 0, 0);
      if (ihalf)
        acc[i][2] = __builtin_amdgcn_mfma_f32_16x16x32_bf16(af, bfr[2], acc[i][2], 0, 0, 0);
      else
        acc[i][3] = __builtin_amdgcn_mfma_f32_16x16x32_bf16(af, bfr[2], acc[i][3], 0, 0, 0);
    }
    __syncthreads();
  }

  // ---- GRU epilogue ----
  int c = ct * 32 + uh * 16 + lm;
  float bcr = bc[c], bcz = bc[256 + c], bcn = bc[512 + c];
  float br  = bih[c] + bhh[c];
  float bz  = bih[256 + c] + bhh[256 + c];
  float bin = bih[512 + c];
  float bhn = bhh[512 + c];
  float local0 = 0.f, local1 = 0.f;
  #pragma unroll
  for (int i = 0; i < 8; ++i) {
    int row0 = m0 + wm + i * 16 + q * 4;
    float4 dg = *(const float4*)&degf[row0];
    #pragma unroll
    for (int reg = 0; reg < 4; ++reg) {
      int row = row0 + reg;
      float deg = (&dg.x)[reg];
      float rg = sigf(acc[i][0][reg] + deg * bcr + br);
      float z  = sigf(acc[i][1][reg] + deg * bcz + bz);
      float n  = tanhf_fast(acc[i][2][reg] + deg * bcn + bin + rg * (acc[i][3][reg] + bhn));
      size_t hoff = (size_t)row * H + c;
      float hp = h[hoff];
      float hnew = (1.f - z) * n + z * hp;
      h[hoff] = hnew;
      hout[hoff] = __float2bfloat16(hnew);
      if (row < NP1) { if (row < NNODES) local0 += hnew; }
      else { if (row - NP1 < NNODES) local1 += hnew; }
    }
  }
  if (local0 != 0.f) atomicAdd(&cs_next[c], local0);
  if (local1 != 0.f) atomicAdd(&cs_next[256 + c], local1);
}

// ---------------- final logits + log_softmax ---------------------------------------
__global__ __launch_bounds__(256) void final_kernel(
    const float* __restrict__ h, const float* __restrict__ Wfc,
    const float* __restrict__ bfc, float* __restrict__ out)
{
  __shared__ float red0[256];
  __shared__ float red1[256];
  int t = threadIdx.x;
  float sn0 = h[(size_t)NNODES * H + t];
  float sn1 = h[((size_t)NP1 + NNODES) * H + t];
  red0[t] = sn0 * Wfc[t]       + sn1 * Wfc[H + t];
  red1[t] = sn0 * Wfc[512 + t] + sn1 * Wfc[512 + H + t];
  __syncthreads();
  for (int s = 128; s > 0; s >>= 1) {
    if (t < s) { red0[t] += red0[t + s]; red1[t] += red1[t + s]; }
    __syncthreads();
  }
  if (t == 0) {
    float l0 = red0[0] + bfc[0], l1 = red1[0] + bfc[1];
    float m = fmaxf(l0, l1);
    float lse = m + logf(expf(l0 - m) + expf(l1 - m));
    out[0] = l0 - lse;
    out[1] = l1 - lse;
  }
}

extern "C" void kernel_launch(void* const* d_in, const int* in_sizes, int n_in,
                              void* d_out, int out_size, void* d_ws, size_t ws_size,
                              hipStream_t stream) {
  const float* b_x   = (const float*)d_in[0];
  const float* b_adj = (const float*)d_in[1];
  const float* a_x   = (const float*)d_in[2];
  const float* a_adj = (const float*)d_in[3];
  const float* Wlin  = (const float*)d_in[4];
  const float* blin  = (const float*)d_in[5];
  const float* Wih   = (const float*)d_in[6];
  const float* bih   = (const float*)d_in[7];
  const float* Whh   = (const float*)d_in[8];
  const float* bhh   = (const float*)d_in[9];
  const float* Wfc   = (const float*)d_in[10];
  const float* bfc   = (const float*)d_in[11];
  float* out = (float*)d_out;

  char* ws = (char*)d_ws;
  size_t off = 0;
  auto alloc = [&](size_t bytes) {
    void* p = ws + off;
    off += (bytes + 255) & ~(size_t)255;
    return p;
  };
  float* h               = (float*)alloc((size_t)MPAD * H * 4);            // 16.5 MB
  __hip_bfloat16* hbf0   = (__hip_bfloat16*)alloc((size_t)MPAD * H * 2);   // 8.3 MB
  __hip_bfloat16* hbf1   = (__hip_bfloat16*)alloc((size_t)MPAD * H * 2);   // 8.3 MB
  __hip_bfloat16* haggbf = (__hip_bfloat16*)alloc((size_t)MPAD * H * 2);   // 8.3 MB
  __hip_bfloat16* Wbig2  = (__hip_bfloat16*)alloc((size_t)768 * 512 * 2);  // 0.8 MB
  float* bc              = (float*)alloc((size_t)768 * 4);
  int* colidx            = (int*)alloc((size_t)2 * NNODES * CAP * 4);      // 4.1 MB
  int* counts            = (int*)alloc((size_t)2 * NNODES * 4 + 1024);
  float* degf            = (float*)alloc((size_t)MPAD * 4);
  float* cs              = (float*)alloc((size_t)(TSTEPS + 1) * 2 * H * 4);

  hipMemsetAsync(cs, 0, (size_t)(TSTEPS + 1) * 2 * H * 4, stream);

  build_ell_kernel<<<4000, 256, 0, stream>>>(b_adj, a_adj, counts, colidx);
  degf_kernel<<<MPAD / 256, 256, 0, stream>>>(counts, degf);
  weights_kernel<<<768, 256, 0, stream>>>(Wih, Wlin, blin, Whh, Wbig2, bc);
  init_h_kernel<<<NRB, 256, 0, stream>>>(b_x, a_x, h, hbf0, cs);

  __hip_bfloat16* ping[2] = { hbf0, hbf1 };
  for (int t = 0; t < TSTEPS; ++t) {
    __hip_bfloat16* hin  = ping[t & 1];
    __hip_bfloat16* hout = ping[(t + 1) & 1];
    spmm_kernel<<<(MTOT + 3) / 4, 256, 0, stream>>>(
        (const unsigned short*)hin, (unsigned short*)haggbf, counts, colidx, cs + t * 2 * H);
    fused_gemm_gru_kernel<<<dim3(MPAD / 256, 8), 256, 0, stream>>>(
        haggbf, hin, Wbig2, degf, bc, bih, bhh, h, hout, cs + (t + 1) * 2 * H);
  }
  final_kernel<<<1, 256, 0, stream>>>(h, Wfc, bfc, out);
}